// Round 2
// baseline (7181.166 us; speedup 1.0000x reference)
//
#include <hip/hip_runtime.h>
#include <hip/hip_bf16.h>
#include <stdint.h>

// Shapes: V=32000, E=H=1024, L=2, B=32, T=128, M=B*T=4096
// Inputs: input_x int32; ALL float tensors fp32 (per reference).
// Output (fp32, concat): output_prob[4096,32000], rnn_hidden[2,32,1024], last_output[32,32000]
// Internally: convert emb/W/hidden to bf16 once, MFMA with fp32 accumulate.

typedef __attribute__((ext_vector_type(8))) short bf16x8;   // 8 bf16 in 4 VGPRs
typedef __attribute__((ext_vector_type(4))) float f32x4;

union U16x8 { uint4 u; bf16x8 v; };
union U64x2 { unsigned long long q[2]; bf16x8 v; };

__device__ __forceinline__ float bf2f(ushort u) {
  union { unsigned int i; float f; } c; c.i = ((unsigned int)u) << 16; return c.f;
}

__device__ __forceinline__ void gload_lds16(const void* g, void* l) {
  // async 16B/lane global->LDS; LDS dest = wave-uniform base + lane*16
  __builtin_amdgcn_global_load_lds(
      (__attribute__((address_space(1))) void*)(uintptr_t)g,
      (__attribute__((address_space(3))) void*)l, 16, 0, 0);
}

// ---------------------------------------------------------------------------
// fp32 -> bf16 conversion (RNE). Each thread converts 4 floats.
// ---------------------------------------------------------------------------
__global__ void cvt_f32_bf16(const float* __restrict__ in, ushort* __restrict__ out, int n4) {
  int i = blockIdx.x * 256 + threadIdx.x;
  if (i < n4) {
    float4 v = ((const float4*)in)[i];
    __hip_bfloat16 b0 = __float2bfloat16(v.x), b1 = __float2bfloat16(v.y),
                   b2 = __float2bfloat16(v.z), b3 = __float2bfloat16(v.w);
    ushort4 o;
    o.x = *(ushort*)&b0; o.y = *(ushort*)&b1; o.z = *(ushort*)&b2; o.w = *(ushort*)&b3;
    ((ushort4*)out)[i] = o;
  }
}

// ---------------------------------------------------------------------------
// Embedding gather + fp32->bf16: A0[i][:] = bf16(emb[input_x[i]][:])
// ---------------------------------------------------------------------------
__global__ void gather_emb(const int* __restrict__ idx, const float* __restrict__ emb,
                           ushort* __restrict__ A0) {
  int i = blockIdx.x;                       // 0..4095 (= b*128 + t)
  int row = idx[i];
  const float4* src = (const float4*)(emb + (size_t)row * 1024);
  float4 a = src[threadIdx.x * 2], b = src[threadIdx.x * 2 + 1];
  float v[8] = {a.x, a.y, a.z, a.w, b.x, b.y, b.z, b.w};
  ushort o[8];
  #pragma unroll
  for (int j = 0; j < 8; ++j) { __hip_bfloat16 t = __float2bfloat16(v[j]); o[j] = *(ushort*)&t; }
  *(uint4*)&A0[(size_t)i * 1024 + threadIdx.x * 8] = *(uint4*)o;
}

// ---------------------------------------------------------------------------
// NT GEMM: C[M,N] = A[M,1024] * Bm[N,1024]^T + bias  (bf16 in, fp32 acc/out)
// 128x128 tile, BK=64, 256 thr (4 waves @ 64x64), global_load_lds staging
// with XOR swizzle (conflict-free ds_read_b128, no padding).
// MODE 0: C stride 1024 (xw scratch).  MODE 1: C stride 32000 (d_out).
// ---------------------------------------------------------------------------
template<int MODE>
__global__ __launch_bounds__(256, 2) void gemm_nt(
    const ushort* __restrict__ A, const ushort* __restrict__ Bm,
    const float* __restrict__ bias, float* __restrict__ C) {
  __shared__ ushort smem[16384];            // 32KB: A tile [0:8192), B tile [8192:16384)
  const int tid = threadIdx.x;
  const int wave = tid >> 6, lane = tid & 63;
  const int ln15 = lane & 15, quad = lane >> 4;
  const int m0 = blockIdx.y * 128, n0 = blockIdx.x * 128;

  // staging: slot p = issue*256 + tid; row = p>>3, phys grp = p&7, logical g = grp ^ (row&7)
  const ushort* aptr[4]; const ushort* bptr[4]; int lbase[4];
  #pragma unroll
  for (int i = 0; i < 4; ++i) {
    int p = i * 256 + tid;
    int row = p >> 3, grp = p & 7;
    int gl = grp ^ (row & 7);
    aptr[i] = A + (size_t)(m0 + row) * 1024 + gl * 8;
    bptr[i] = Bm + (size_t)(n0 + row) * 1024 + gl * 8;
    lbase[i] = (i * 256 + wave * 64) * 8;   // ushort idx of wave-uniform LDS base
  }

  f32x4 acc[4][4];
  #pragma unroll
  for (int i = 0; i < 4; ++i)
    #pragma unroll
    for (int j = 0; j < 4; ++j) acc[i][j] = (f32x4)(0.f);

  const int wm = (wave & 1) * 64, wn = (wave >> 1) * 64;

  for (int kt = 0; kt < 16; ++kt) {
    const int k0 = kt * 64;
    #pragma unroll
    for (int i = 0; i < 4; ++i) {
      gload_lds16(aptr[i] + k0, &smem[lbase[i]]);
      gload_lds16(bptr[i] + k0, &smem[8192 + lbase[i]]);
    }
    __syncthreads();
    #pragma unroll
    for (int ks = 0; ks < 2; ++ks) {
      bf16x8 af[4], bfr[4];
      const int g = ks * 4 + quad;
      #pragma unroll
      for (int mt = 0; mt < 4; ++mt) {
        int r = wm + mt * 16 + ln15;
        U16x8 u; u.u = *(const uint4*)&smem[(r * 8 + (g ^ (r & 7))) * 8];
        af[mt] = u.v;
      }
      #pragma unroll
      for (int nt = 0; nt < 4; ++nt) {
        int r = wn + nt * 16 + ln15;
        U16x8 u; u.u = *(const uint4*)&smem[8192 + (r * 8 + (g ^ (r & 7))) * 8];
        bfr[nt] = u.v;
      }
      #pragma unroll
      for (int mt = 0; mt < 4; ++mt)
        #pragma unroll
        for (int nt = 0; nt < 4; ++nt)
          acc[mt][nt] = __builtin_amdgcn_mfma_f32_16x16x32_bf16(af[mt], bfr[nt], acc[mt][nt], 0, 0, 0);
    }
    __syncthreads();
  }

  const size_t ldc = (MODE == 0) ? 1024 : 32000;
  #pragma unroll
  for (int nt = 0; nt < 4; ++nt) {
    int col = n0 + wn + nt * 16 + ln15;
    float bv = bias[col];
    #pragma unroll
    for (int mt = 0; mt < 4; ++mt)
      #pragma unroll
      for (int r = 0; r < 4; ++r) {
        int row = m0 + wm + mt * 16 + quad * 4 + r;
        C[(size_t)row * ldc + col] = acc[mt][nt][r] + bv;
      }
  }
}

// ---------------------------------------------------------------------------
// Persistent RNN layer: 16 WGs x 256 thr; wave owns 16 features, W_hh
// B-fragments live in 128 VGPRs for the whole kernel. h exchanged via
// agent-scope atomics (L3-coherent); steps sequenced by release-add /
// acquire-spin on ctr[t]. Y layout row i = b*128 + t (bf16).
// ---------------------------------------------------------------------------
__global__ __launch_bounds__(256, 1) void rnn_layer(
    const ushort* __restrict__ Whh,   // [1024][1024] bf16 (converted)
    const float* __restrict__ bhh,    // [1024] fp32
    const float* __restrict__ xw,     // [4096][1024] fp32 (x@W_ih^T + b_ih)
    const ushort* __restrict__ h0,    // [32][1024] bf16 (converted initial hidden)
    ushort* __restrict__ Y,           // [4096][1024] bf16 outputs (= h_t rows)
    unsigned int* __restrict__ ctr) { // [128], pre-zeroed
  const int tid = threadIdx.x;
  const int wave = tid >> 6, lane = tid & 63;
  const int ln15 = lane & 15, quad = lane >> 4;
  const int f = blockIdx.x * 64 + wave * 16 + ln15;   // this lane's feature (n)

  // B-fragments: Whh[f][kk*32 + quad*8 + j], kk=0..31  -> 128 VGPRs
  bf16x8 bq[32];
  #pragma unroll
  for (int kk = 0; kk < 32; ++kk) {
    U16x8 u; u.u = *(const uint4*)&Whh[(size_t)f * 1024 + kk * 32 + quad * 8];
    bq[kk] = u.v;
  }
  const float bias = bhh[f];

  for (int t = 0; t < 128; ++t) {
    if (t > 0) {
      while (__hip_atomic_load(&ctr[t - 1], __ATOMIC_ACQUIRE, __HIP_MEMORY_SCOPE_AGENT) < 16u)
        __builtin_amdgcn_s_sleep(2);
    }
    const ushort* s0p; const ushort* s1p;
    if (t == 0) {
      s0p = h0 + (size_t)ln15 * 1024;
      s1p = h0 + (size_t)(ln15 + 16) * 1024;
    } else {
      s0p = Y + ((size_t)ln15 * 128 + (t - 1)) * 1024;
      s1p = Y + ((size_t)(ln15 + 16) * 128 + (t - 1)) * 1024;
    }
    f32x4 acc0 = (f32x4)(0.f), acc1 = (f32x4)(0.f);
    #pragma unroll 8
    for (int kk = 0; kk < 32; ++kk) {
      int k = kk * 32 + quad * 8;
      U64x2 a0, a1;
      const unsigned long long* p0 = (const unsigned long long*)(s0p + k);
      const unsigned long long* p1 = (const unsigned long long*)(s1p + k);
      a0.q[0] = __hip_atomic_load(p0,     __ATOMIC_RELAXED, __HIP_MEMORY_SCOPE_AGENT);
      a0.q[1] = __hip_atomic_load(p0 + 1, __ATOMIC_RELAXED, __HIP_MEMORY_SCOPE_AGENT);
      a1.q[0] = __hip_atomic_load(p1,     __ATOMIC_RELAXED, __HIP_MEMORY_SCOPE_AGENT);
      a1.q[1] = __hip_atomic_load(p1 + 1, __ATOMIC_RELAXED, __HIP_MEMORY_SCOPE_AGENT);
      acc0 = __builtin_amdgcn_mfma_f32_16x16x32_bf16(a0.v, bq[kk], acc0, 0, 0, 0);
      acc1 = __builtin_amdgcn_mfma_f32_16x16x32_bf16(a1.v, bq[kk], acc1, 0, 0, 0);
    }
    // epilogue: D row = batch (quad*4+r [+16]), col = feature f
    #pragma unroll
    for (int mt = 0; mt < 2; ++mt) {
      f32x4 a = mt ? acc1 : acc0;
      #pragma unroll
      for (int r = 0; r < 4; ++r) {
        int row = mt * 16 + quad * 4 + r;                 // batch index
        float val = a[r] + xw[((size_t)row * 128 + t) * 1024 + f] + bias;
        float th = tanhf(val);
        __hip_bfloat16 hb = __float2bfloat16(th);
        __hip_atomic_store((unsigned short*)&Y[((size_t)row * 128 + t) * 1024 + f],
                           *(unsigned short*)&hb, __ATOMIC_RELAXED, __HIP_MEMORY_SCOPE_AGENT);
      }
    }
    asm volatile("s_waitcnt vmcnt(0)" ::: "memory");      // drain stores before barrier
    __syncthreads();
    if (tid == 0)
      __hip_atomic_fetch_add(&ctr[t], 1u, __ATOMIC_RELEASE, __HIP_MEMORY_SCOPE_AGENT);
  }
}

// ---------------------------------------------------------------------------
// rnn_hidden = bf2f([Y0[:,127,:], Y1[:,127,:]]); last_output = prob rows t=127
// ---------------------------------------------------------------------------
__global__ void finalize(const ushort* __restrict__ Y0, const ushort* __restrict__ Y1,
                         float* __restrict__ out) {
  int b = blockIdx.x, tid = threadIdx.x;
  const size_t PROB = (size_t)4096 * 32000;               // 131,072,000
  const float4* src = (const float4*)(out + (size_t)(b * 128 + 127) * 32000);
  float4* dst = (float4*)(out + PROB + 65536 + (size_t)b * 32000);
  for (int s = tid; s < 8000; s += 256) dst[s] = src[s];
  {
    int e = tid * 4;                                      // 256*4 = 1024 per layer
    const ushort* s0 = Y0 + (size_t)(b * 128 + 127) * 1024 + e;
    const ushort* s1 = Y1 + (size_t)(b * 128 + 127) * 1024 + e;
    float4 v0, v1;
    v0.x = bf2f(s0[0]); v0.y = bf2f(s0[1]); v0.z = bf2f(s0[2]); v0.w = bf2f(s0[3]);
    v1.x = bf2f(s1[0]); v1.y = bf2f(s1[1]); v1.z = bf2f(s1[2]); v1.w = bf2f(s1[3]);
    *(float4*)&out[PROB + (size_t)b * 1024 + e] = v0;
    *(float4*)&out[PROB + 32768 + (size_t)b * 1024 + e] = v1;
  }
}

__global__ void init_ctr(unsigned int* c) { c[threadIdx.x] = 0; }  // 256 covers both layers

// ---------------------------------------------------------------------------
extern "C" void kernel_launch(void* const* d_in, const int* in_sizes, int n_in,
                              void* d_out, int out_size, void* d_ws, size_t ws_size,
                              hipStream_t stream) {
  (void)in_sizes; (void)n_in; (void)out_size; (void)ws_size;
  const int*   input_x = (const int*)  d_in[0];
  const float* hidden  = (const float*)d_in[1];
  const float* emb     = (const float*)d_in[2];
  const float* W_ih0   = (const float*)d_in[3];
  const float* W_hh0   = (const float*)d_in[4];
  const float* b_ih0   = (const float*)d_in[5];
  const float* b_hh0   = (const float*)d_in[6];
  const float* W_ih1   = (const float*)d_in[7];
  const float* W_hh1   = (const float*)d_in[8];
  const float* b_ih1   = (const float*)d_in[9];
  const float* b_hh1   = (const float*)d_in[10];
  const float* W_out   = (const float*)d_in[11];
  const float* b_out   = (const float*)d_in[12];

  const size_t MB = 1024 * 1024;
  char* ws = (char*)d_ws;
  ushort*       A0   = (ushort*)(ws);               // 8 MB  [4096][1024] bf16
  float*        xw   = (float*) (ws + 8  * MB);     // 16 MB [4096][1024] f32
  ushort*       Y0   = (ushort*)(ws + 24 * MB);     // 8 MB
  ushort*       Y1   = (ushort*)(ws + 32 * MB);     // 8 MB
  ushort*       Wb_ih0 = (ushort*)(ws + 40 * MB);   // 2 MB each
  ushort*       Wb_hh0 = (ushort*)(ws + 42 * MB);
  ushort*       Wb_ih1 = (ushort*)(ws + 44 * MB);
  ushort*       Wb_hh1 = (ushort*)(ws + 46 * MB);
  ushort*       Wb_out = (ushort*)(ws + 48 * MB);   // 65,536,000 B
  ushort*       h0b    = (ushort*)(ws + 116 * MB);  // 131,072 B [2][32][1024] bf16
  unsigned int* ctr    = (unsigned int*)(ws + 117 * MB); // 256 u32

  init_ctr<<<1, 256, 0, stream>>>(ctr);
  cvt_f32_bf16<<<1024, 256, 0, stream>>>(W_ih0, Wb_ih0, 262144);
  cvt_f32_bf16<<<1024, 256, 0, stream>>>(W_hh0, Wb_hh0, 262144);
  cvt_f32_bf16<<<1024, 256, 0, stream>>>(W_ih1, Wb_ih1, 262144);
  cvt_f32_bf16<<<1024, 256, 0, stream>>>(W_hh1, Wb_hh1, 262144);
  cvt_f32_bf16<<<32000, 256, 0, stream>>>(W_out, Wb_out, 8192000);
  cvt_f32_bf16<<<64, 256, 0, stream>>>(hidden, h0b, 16384);
  gather_emb<<<4096, 128, 0, stream>>>(input_x, emb, A0);

  gemm_nt<0><<<dim3(8, 32), 256, 0, stream>>>(A0, Wb_ih0, b_ih0, xw);
  rnn_layer<<<16, 256, 0, stream>>>(Wb_hh0, b_hh0, xw, h0b, Y0, ctr);
  gemm_nt<0><<<dim3(8, 32), 256, 0, stream>>>(Y0, Wb_ih1, b_ih1, xw);
  rnn_layer<<<16, 256, 0, stream>>>(Wb_hh1, b_hh1, xw, h0b + 32768, Y1, ctr + 128);
  gemm_nt<1><<<dim3(250, 32), 256, 0, stream>>>(Y1, Wb_out, b_out, (float*)d_out);
  finalize<<<32, 256, 0, stream>>>(Y0, Y1, (float*)d_out);
}